// Round 9
// baseline (228.604 us; speedup 1.0000x reference)
//
#include <hip/hip_runtime.h>
#include <cstdint>
#include <cstddef>

typedef short s16x8 __attribute__((ext_vector_type(8)));
typedef float f32x4 __attribute__((ext_vector_type(4)));

#define MFMA16(a, b, c) __builtin_amdgcn_mfma_f32_16x16x32_bf16((a), (b), (c), 0, 0, 0)

constexpr int LDW = 136;  // padded stride for P buffer (64q x 128k)

__device__ __forceinline__ short f2bf(float f) {
    unsigned u = __builtin_bit_cast(unsigned, f);
    u += 0x7FFFu + ((u >> 16) & 1u);   // RNE
    return (short)(u >> 16);
}
__device__ __forceinline__ float bf2f(short s) {
    unsigned u = ((unsigned)(unsigned short)s) << 16;
    return __builtin_bit_cast(float, u);
}
__device__ __forceinline__ unsigned pack2(float a, float b) {
    return (unsigned)(unsigned short)f2bf(a) | ((unsigned)(unsigned short)f2bf(b) << 16);
}
// truncating pack (P >= 0: bias <= 1 bf16 ulp) — saves VALU in hot loop
__device__ __forceinline__ unsigned pack2t(float a, float b) {
    unsigned ua = __builtin_bit_cast(unsigned, a);
    unsigned ub = __builtin_bit_cast(unsigned, b);
    return (ua >> 16) | (ub & 0xFFFF0000u);
}

// async 16B/lane global->LDS copy (global_load_lds_dwordx4). Global address is
// per-lane; LDS dest is wave-uniform base + lane*16.
__device__ __forceinline__ void async_ld16(const void* g, void* l) {
    __builtin_amdgcn_global_load_lds(
        (const __attribute__((address_space(1))) unsigned int*)g,
        (__attribute__((address_space(3))) unsigned int*)l, 16, 0, 0);
}

// ---------------------------------------------------------------------------
// Kernel 0: fp32 -> bf16 convert of x and all four weights (once per call).
// ---------------------------------------------------------------------------
__global__ __launch_bounds__(256) void convert_kernel(
    const float* __restrict__ x, const float* __restrict__ Wq,
    const float* __restrict__ Wk, const float* __restrict__ Wv,
    const float* __restrict__ Wo, short* __restrict__ xb, short* __restrict__ wb) {
    const size_t f = ((size_t)blockIdx.x * 256 + threadIdx.x) * 8;   // 8 floats/thread
    const float* src;
    short* dst;
    if (f < 4194304) { src = x + f; dst = xb + f; }
    else {
        size_t wo = f - 4194304;
        int seg = (int)(wo >> 20);
        const float* ws4[4] = {Wq, Wk, Wv, Wo};
        src = ws4[seg] + (wo & 1048575u);
        dst = wb + wo;
    }
    float4 a = ((const float4*)src)[0];
    float4 b = ((const float4*)src)[1];
    *(uint4*)dst = make_uint4(pack2(a.x, a.y), pack2(a.z, a.w),
                              pack2(b.x, b.y), pack2(b.z, b.w));
}

// ---------------------------------------------------------------------------
// Kernel 1: QKV projection, m97-structure (128x128 tile, BK=64, async stage).
// Q,K -> [B,H,T,D] bf16 (unrotated); V -> [B,H,D,T] bf16 (pre-transposed).
// RoPE is a separate kernel: fusing it here cost ~20us (VGPR cliff, R8).
// ---------------------------------------------------------------------------
__global__ __launch_bounds__(256) void qkv_kernel(
    const short* __restrict__ xb, const short* __restrict__ wb,
    short* __restrict__ Qo, short* __restrict__ Ko, short* __restrict__ VTo) {
    __shared__ __align__(16) short sA[128 * 64];
    __shared__ __align__(16) short sB[128 * 64];
    const int tid = threadIdx.x;
    const int w = tid >> 6, lane = tid & 63, quad = lane >> 4, l15 = lane & 15;
    const int wm = w & 1, wn = w >> 1;
    const int bx = blockIdx.x, by = blockIdx.y;
    const int m0 = by * 128;
    const int nb = bx * 128;

    f32x4 acc[4][4];
#pragma unroll
    for (int i = 0; i < 4; i++)
#pragma unroll
        for (int j = 0; j < 4; j++) acc[i][j] = f32x4{0.f, 0.f, 0.f, 0.f};

    for (int kb = 0; kb < 16; kb++) {
        const int k0 = kb * 64;
        if (kb) __syncthreads();
#pragma unroll
        for (int i = 0; i < 4; i++) {
            int c = i * 256 + tid;             // 16B chunk id
            int row = c >> 3, col8 = (c & 7) * 8;
            async_ld16(xb + (size_t)(m0 + row) * 1024 + k0 + col8,
                       &sA[(i * 256 + w * 64) * 8]);
            async_ld16(wb + (size_t)(nb + row) * 1024 + k0 + col8,
                       &sB[(i * 256 + w * 64) * 8]);
        }
        __syncthreads();
#pragma unroll
        for (int ks = 0; ks < 2; ks++) {
            s16x8 av[4], bv[4];
#pragma unroll
            for (int at = 0; at < 4; at++)
                av[at] = *(const s16x8*)&sA[(wm * 64 + at * 16 + l15) * 64 + ks * 32 + quad * 8];
#pragma unroll
            for (int bt = 0; bt < 4; bt++)
                bv[bt] = *(const s16x8*)&sB[(wn * 64 + bt * 16 + l15) * 64 + ks * 32 + quad * 8];
#pragma unroll
            for (int at = 0; at < 4; at++)
#pragma unroll
                for (int bt = 0; bt < 4; bt++)
                    acc[at][bt] = MFMA16(av[at], bv[bt], acc[at][bt]);
        }
    }

    const int wsel = bx >> 3;                 // 0=q 1=k 2=v
    const int h = (bx & 7) * 2 + wn;          // head (uniform per wave)
    if (wsel == 2) {
#pragma unroll
        for (int at = 0; at < 4; at++) {
            int m = m0 + wm * 64 + at * 16 + quad * 4;
            int b = m >> 11, t0 = m & 2047;
            size_t base = ((size_t)((b * 16 + h) * 64)) * 2048;
#pragma unroll
            for (int bt = 0; bt < 4; bt++) {
                int d = bt * 16 + l15;
                unsigned lo = pack2(acc[at][bt][0], acc[at][bt][1]);
                unsigned hi = pack2(acc[at][bt][2], acc[at][bt][3]);
                *(uint2*)&VTo[base + (size_t)d * 2048 + t0] = make_uint2(lo, hi);
            }
        }
    } else {
        short* Out = (wsel == 0) ? Qo : Ko;
#pragma unroll
        for (int at = 0; at < 4; at++)
#pragma unroll
            for (int r = 0; r < 4; r++) {
                int m = m0 + wm * 64 + at * 16 + quad * 4 + r;
                int b = m >> 11, t = m & 2047;
                size_t base = (((size_t)(b * 16 + h)) * 2048 + t) * 64;
#pragma unroll
                for (int bt = 0; bt < 4; bt++)
                    Out[base + bt * 16 + l15] = f2bf(acc[at][bt][r]);
            }
    }
}

// ---------------------------------------------------------------------------
// Kernel 2: RoPE in-place on Q and K. Q pre-scaled by 0.125*log2(e) (exp2
// domain softmax). Native v_sin/v_cos (revolutions).
// ---------------------------------------------------------------------------
__global__ __launch_bounds__(256) void rope_kernel(short* __restrict__ Q, short* __restrict__ K) {
    const int rid = blockIdx.x * 256 + threadIdx.x;   // 0..131071
    const bool isK = (rid & 65536) != 0;
    short* buf = isK ? K : Q;
    const float sc = isK ? 1.0f : 0.18033688011112042f;   // 1/8 * log2(e)
    const int r2 = rid & 65535;          // bh*2048 + t
    const int t = r2 & 2047;
    short* row = buf + (size_t)r2 * 64;

    unsigned wv[32];
    const uint4* rp = (const uint4*)row;
#pragma unroll
    for (int c = 0; c < 8; c++) {
        uint4 v = rp[c];
        wv[c * 4 + 0] = v.x; wv[c * 4 + 1] = v.y; wv[c * 4 + 2] = v.z; wv[c * 4 + 3] = v.w;
    }
    float y1[32], y2[32];
    const float tf = (float)t;
#pragma unroll
    for (int i = 0; i < 32; i++) {
        float x1 = bf2f((short)(wv[i] & 0xFFFFu));
        float x2 = bf2f((short)(wv[i] >> 16));
        float inv = exp2f((float)i * -0.4152410118609203f);  // 10000^(-i/32), const-folded
        float rev = tf * inv * 0.15915494309189535f;         // fr / 2pi
        rev = rev - floorf(rev);
        float sn = __builtin_amdgcn_sinf(rev);               // sin(rev*2pi) = sin(fr)
        float cs = __builtin_amdgcn_cosf(rev);
        y1[i] = (x1 * cs - x2 * sn) * sc;
        y2[i] = (x1 * sn + x2 * cs) * sc;
    }
    unsigned ow[32];
#pragma unroll
    for (int i = 0; i < 16; i++) ow[i] = pack2(y1[2 * i], y1[2 * i + 1]);
#pragma unroll
    for (int i = 0; i < 16; i++) ow[16 + i] = pack2(y2[2 * i], y2[2 * i + 1]);
    uint4* wp = (uint4*)row;
#pragma unroll
    for (int c = 0; c < 8; c++)
        wp[c] = make_uint4(ow[c * 4 + 0], ow[c * 4 + 1], ow[c * 4 + 2], ow[c * 4 + 3]);
}

// ---------------------------------------------------------------------------
// Kernel 3: causal flash attention — 64 queries x 128-key blocks, 80 units/bh,
// key-split partials, NO-MAX exp2 softmax (scores bounded; exp2(-inf)=0 masks).
// K/V staged via global_load_lds width-16 into UNPADDED tiles: no VGPR
// round-trip, no LDS write traffic, no staging address VALU (m97 lever).
// P buffer stays padded (manual writes). Partial O + l out; combine merges.
// ---------------------------------------------------------------------------
__global__ __launch_bounds__(256) void attn_kernel(
    const short* __restrict__ Q, const short* __restrict__ K,
    const short* __restrict__ VT, short* __restrict__ paO, float* __restrict__ ml) {
    __shared__ __align__(16) short sQP[64 * LDW];   // Q (64x64) then P (64q x 128k)
    __shared__ __align__(16) short sK[128 * 64];    // 128 keys x 64 d, unpadded
    __shared__ __align__(16) short sVT[64 * 128];   // 64 d x 128 keys, unpadded

    const int tid = threadIdx.x;
    const int w = tid >> 6, lane = tid & 63, quad = lane >> 4, l15 = lane & 15;
    const int u = 79 - blockIdx.x;       // largest-qt units first
    const int bh = blockIdx.y;           // 0..31

    int qt, c;
    if (u < 8)       { qt = u; c = 0; }
    else if (u < 24) { int v = u - 8;  qt = 8 + (v >> 1); c = v & 1; }
    else if (u < 48) { int v = u - 24; qt = 16 + v / 3;   c = v - 3 * (qt - 16); }
    else             { int v = u - 48; qt = 24 + (v >> 2); c = v & 3; }
    const int kbDiag = qt >> 1;              // 128-key block containing the diagonal
    const int kb0 = c * 4;
    const int kb1 = min(kb0 + 3, kbDiag);

    const short* Qp = Q + (size_t)bh * 2048 * 64;
    const short* Kp = K + (size_t)bh * 2048 * 64;
    const short* Vp = VT + (size_t)bh * 64 * 2048;   // [d][t]

    // per-thread async source coordinates (fixed across iterations)
    const int kRow = tid >> 3, kCol = (tid & 7) * 8;     // sK: 128 rows x 8 col-chunks... (per 256-thread slab of 1024 chunks)
    const int vRow = tid >> 4, vCol = (tid & 15) * 8;    // sVT: 64 rows x 16 col-chunks

    // stage Q tile (64 rows x 64 dims) into sQP (stride LDW)
#pragma unroll
    for (int i = 0; i < 2; i++) {
        int p = tid + i * 256;       // 512 uint4 slots: 64 rows x 8
        int row = p >> 3, c8 = p & 7;
        uint4 v = *(const uint4*)(Qp + (size_t)(qt * 64 + row) * 64 + c8 * 8);
        *(uint4*)&sQP[row * LDW + c8 * 8] = v;
    }
    __syncthreads();
    s16x8 aq[2];
#pragma unroll
    for (int ks = 0; ks < 2; ks++)
        aq[ks] = *(const s16x8*)&sQP[(w * 16 + l15) * LDW + ks * 32 + quad * 8];

    f32x4 o[4];
#pragma unroll
    for (int i = 0; i < 4; i++) o[i] = f32x4{0.f, 0.f, 0.f, 0.f};
    float lrun = 0.f;                // per-lane partial sum (quad-reduced at end)
    const int q_idx = qt * 64 + w * 16 + l15;

    for (int kb = kb0; kb <= kb1; kb++) {
        __syncthreads();             // prior iter's readers done (covers aq reads iter 0)
        // async stage K (128x64) and V^T (64x128): 4+4 global_load_lds_dwordx4
#pragma unroll
        for (int i = 0; i < 4; i++) {
            // sK chunk p = tid + i*256: row = p>>3, col8 = (p&7)*8
            async_ld16(Kp + (size_t)(kb * 128 + (i * 32 + kRow)) * 64 + kCol,
                       &sK[(i * 256 + w * 64) * 8]);
            // sVT chunk p: row = p>>4, col16 = (p&15)*8
            async_ld16(Vp + (size_t)(i * 16 + vRow) * 2048 + kb * 128 + vCol,
                       &sVT[(i * 256 + w * 64) * 8]);
        }
        __syncthreads();

        // S^T: 128 keys x 16 queries per wave. A = K rows (keys), B = Q^T.
        f32x4 sa[8];
#pragma unroll
        for (int i = 0; i < 8; i++) sa[i] = f32x4{0.f, 0.f, 0.f, 0.f};
#pragma unroll
        for (int ks = 0; ks < 2; ks++) {
#pragma unroll
            for (int ct = 0; ct < 8; ct++) {
                s16x8 kf = *(const s16x8*)&sK[(ct * 16 + l15) * 64 + ks * 32 + quad * 8];
                sa[ct] = MFMA16(kf, aq[ks], sa[ct]);
            }
        }

        float ps[8][4];
#pragma unroll
        for (int ct = 0; ct < 8; ct++)
#pragma unroll
            for (int r = 0; r < 4; r++) ps[ct][r] = sa[ct][r];

        if (kb == kbDiag) {          // uniform branch: only the diagonal block masks
#pragma unroll
            for (int ct = 0; ct < 8; ct++) {
                int kbase = kb * 128 + ct * 16 + quad * 4;
#pragma unroll
                for (int r = 0; r < 4; r++)
                    if ((kbase + r) > q_idx) ps[ct][r] = -INFINITY;
            }
        }

        // P = exp2(s) (no max subtraction), accumulate per-lane l
        float cm[8];
#pragma unroll
        for (int ct = 0; ct < 8; ct++) {
#pragma unroll
            for (int r = 0; r < 4; r++) ps[ct][r] = exp2f(ps[ct][r]);
            cm[ct] = (ps[ct][0] + ps[ct][1]) + (ps[ct][2] + ps[ct][3]);
        }
        lrun += ((cm[0] + cm[1]) + (cm[2] + cm[3])) + ((cm[4] + cm[5]) + (cm[6] + cm[7]));

        // P^T (C-layout) -> sQP rows = query (wave-private), 8x ds_write_b64
#pragma unroll
        for (int ct = 0; ct < 8; ct++) {
            unsigned lo = pack2t(ps[ct][0], ps[ct][1]);
            unsigned hi = pack2t(ps[ct][2], ps[ct][3]);
            *(uint2*)&sQP[(w * 16 + l15) * LDW + ct * 16 + quad * 4] = make_uint2(lo, hi);
        }
        // no barrier: rows are wave-private, same-wave DS ops in-order

        // O += P V  (A = P rows=query, k = 128 keys; B = V^T rows = d)
#pragma unroll
        for (int ks2 = 0; ks2 < 4; ks2++) {
            s16x8 pa = *(const s16x8*)&sQP[(w * 16 + l15) * LDW + ks2 * 32 + quad * 8];
#pragma unroll
            for (int ct = 0; ct < 4; ct++) {
                s16x8 vb = *(const s16x8*)&sVT[(ct * 16 + l15) * 128 + ks2 * 32 + quad * 8];
                o[ct] = MFMA16(pa, vb, o[ct]);
            }
        }
    }

    // epilogue: UNNORMALIZED partial O (bf16) + l (fp32, per query)
    const size_t pbase = ((size_t)(bh * 80 + u)) * 4096;
#pragma unroll
    for (int r = 0; r < 4; r++) {
        int row = w * 16 + quad * 4 + r;
#pragma unroll
        for (int ct = 0; ct < 4; ct++)
            paO[pbase + row * 64 + ct * 16 + l15] = f2bf(o[ct][r]);
    }
    lrun += __shfl_xor(lrun, 16);
    lrun += __shfl_xor(lrun, 32);
    if (quad == 0)
        ml[(bh * 80 + u) * 64 + w * 16 + l15] = lrun;
}

// ---------------------------------------------------------------------------
// Kernel 3b: combine partials (no-max scheme: L = sum l_i, Y = sum O_i / L).
// ---------------------------------------------------------------------------
__global__ __launch_bounds__(256) void combine_kernel(
    const short* __restrict__ paO, const float* __restrict__ ml, short* __restrict__ Y) {
    const int qt = blockIdx.x, bh = blockIdx.y;
    const int b = bh >> 4, h = bh & 15;
    const int nch = (qt >> 3) + 1;
    int base;
    if (qt < 8) base = qt;
    else if (qt < 16) base = 8 + 2 * (qt - 8);
    else if (qt < 24) base = 24 + 3 * (qt - 16);
    else base = 48 + 4 * (qt - 24);

    const int row = threadIdx.x >> 2;
    const int cq = (threadIdx.x & 3) * 16;

    float L = 0.f;
    for (int i = 0; i < nch; i++)
        L += ml[(bh * 80 + base + i) * 64 + row];
    const float inv = 1.0f / L;

    float acc[16];
#pragma unroll
    for (int j = 0; j < 16; j++) acc[j] = 0.f;
    for (int i = 0; i < nch; i++) {
        const short* p = paO + ((size_t)(bh * 80 + base + i)) * 4096 + row * 64 + cq;
        uint4 v0 = ((const uint4*)p)[0];
        uint4 v1 = ((const uint4*)p)[1];
        unsigned vs[8] = {v0.x, v0.y, v0.z, v0.w, v1.x, v1.y, v1.z, v1.w};
#pragma unroll
        for (int j = 0; j < 8; j++) {
            acc[2 * j + 0] += bf2f((short)(vs[j] & 0xFFFFu));
            acc[2 * j + 1] += bf2f((short)(vs[j] >> 16));
        }
    }
    const int t = qt * 64 + row;
    short* yp = Y + ((size_t)(b * 2048 + t)) * 1024 + h * 64 + cq;
    unsigned ow[8];
#pragma unroll
    for (int j = 0; j < 8; j++) ow[j] = pack2(acc[2 * j] * inv, acc[2 * j + 1] * inv);
    ((uint4*)yp)[0] = make_uint4(ow[0], ow[1], ow[2], ow[3]);
    ((uint4*)yp)[1] = make_uint4(ow[4], ow[5], ow[6], ow[7]);
}

// ---------------------------------------------------------------------------
// Kernel 4: output projection, 64x128 tiles -> grid (8,64)=512 blocks (2/CU).
// Wave w owns a 64x32 output slab. fp32 out.
// ---------------------------------------------------------------------------
__global__ __launch_bounds__(256) void oproj_kernel(
    const short* __restrict__ Yb, const short* __restrict__ Wob, float* __restrict__ out) {
    __shared__ __align__(16) short sA[64 * 64];
    __shared__ __align__(16) short sB[128 * 64];
    const int tid = threadIdx.x;
    const int w = tid >> 6, lane = tid & 63, quad = lane >> 4, l15 = lane & 15;
    const int m0 = blockIdx.y * 64;
    const int nb = blockIdx.x * 128;

    f32x4 acc[4][2];
#pragma unroll
    for (int i = 0; i < 4; i++)
#pragma unroll
        for (int j = 0; j < 2; j++) acc[i][j] = f32x4{0.f, 0.f, 0.f, 0.f};

    for (int kb = 0; kb < 16; kb++) {
        const int k0 = kb * 64;
        if (kb) __syncthreads();
#pragma unroll
        for (int i = 0; i < 2; i++) {      // A: 64x64 shorts = 512 chunks
            int c = i * 256 + tid;
            int row = c >> 3, col8 = (c & 7) * 8;
            async_ld16(Yb + (size_t)(m0 + row) * 1024 + k0 + col8,
                       &sA[(i * 256 + w * 64) * 8]);
        }
#pragma unroll
        for (int i = 0; i < 4; i++) {      // B: 128x64 shorts = 1024 chunks
            int c = i * 256 + tid;
            int row = c >> 3, col8 = (c & 7) * 8;
            async_ld16(Wob + (size_t)(nb + row) * 1024 + k0 + col8,
                       &sB[(i * 256 + w * 64) * 8]);
        }
        __syncthreads();
#pragma unroll
        for (int ks = 0; ks < 2; ks++) {
            s16x8 av[4], bv[2];
#pragma unroll
            for (int at = 0; at < 4; at++)
                av[at] = *(const s16x8*)&sA[(at * 16 + l15) * 64 + ks * 32 + quad * 8];
#pragma unroll
            for (int bt = 0; bt < 2; bt++)
                bv[bt] = *(const s16x8*)&sB[(w * 32 + bt * 16 + l15) * 64 + ks * 32 + quad * 8];
#pragma unroll
            for (int at = 0; at < 4; at++)
#pragma unroll
                for (int bt = 0; bt < 2; bt++)
                    acc[at][bt] = MFMA16(av[at], bv[bt], acc[at][bt]);
        }
    }
#pragma unroll
    for (int at = 0; at < 4; at++)
#pragma unroll
        for (int r = 0; r < 4; r++) {
            int m = m0 + at * 16 + quad * 4 + r;
#pragma unroll
            for (int bt = 0; bt < 2; bt++) {
                int n = nb + w * 32 + bt * 16 + l15;
                out[(size_t)m * 1024 + n] = acc[at][bt][r];
            }
        }
}

extern "C" void kernel_launch(void* const* d_in, const int* in_sizes, int n_in,
                              void* d_out, int out_size, void* d_ws, size_t ws_size,
                              hipStream_t stream) {
    (void)in_sizes; (void)n_in; (void)out_size; (void)ws_size;
    const float* x  = (const float*)d_in[0];
    const float* Wq = (const float*)d_in[1];
    const float* Wk = (const float*)d_in[2];
    const float* Wv = (const float*)d_in[3];
    const float* Wo = (const float*)d_in[4];
    float* out = (float*)d_out;

    const size_t NE = (size_t)2 * 16 * 2048 * 64;   // 4M elems per tensor
    short* Q   = (short*)d_ws;
    short* K   = Q + NE;
    short* VT  = K + NE;          // [B,H,D,T]
    short* Y   = VT + NE;         // attn output [B,T,C] bf16
    short* xb  = Y;               // x bf16 ALIASES Y: consumed by qkv before combine writes Y
    short* wb  = Y + NE;          // [Wq|Wk|Wv|Wo] bf16, 4M elems
    short* paO = wb + NE;         // partial O: 32 bh x 80 units x 64x64 bf16 = 21 MB
    float* ml  = (float*)(paO + (size_t)32 * 80 * 4096);   // l: 32x80x64 fp32

    convert_kernel<<<4096, 256, 0, stream>>>(x, Wq, Wk, Wv, Wo, xb, wb);
    qkv_kernel<<<dim3(24, 32), 256, 0, stream>>>(xb, wb, Q, K, VT);
    rope_kernel<<<512, 256, 0, stream>>>(Q, K);
    attn_kernel<<<dim3(80, 32), 256, 0, stream>>>(Q, K, VT, paO, ml);
    combine_kernel<<<dim3(32, 32), 256, 0, stream>>>(paO, ml, Y);
    oproj_kernel<<<dim3(8, 64), 256, 0, stream>>>(Y, wb + 3 * 1048576, out);
}

// Round 10
// 205.354 us; speedup vs baseline: 1.1132x; 1.1132x over previous
//
#include <hip/hip_runtime.h>
#include <cstdint>
#include <cstddef>

typedef short s16x8 __attribute__((ext_vector_type(8)));
typedef float f32x4 __attribute__((ext_vector_type(4)));

#define MFMA16(a, b, c) __builtin_amdgcn_mfma_f32_16x16x32_bf16((a), (b), (c), 0, 0, 0)

constexpr int LDP = 72;   // stride for 64-col tiles (bf16): staging conflict-free, frag reads 2-way
constexpr int LDW = 136;  // stride for 128-col tiles (bf16): same properties

__device__ __forceinline__ short f2bf(float f) {
    unsigned u = __builtin_bit_cast(unsigned, f);
    u += 0x7FFFu + ((u >> 16) & 1u);   // RNE
    return (short)(u >> 16);
}
__device__ __forceinline__ float bf2f(short s) {
    unsigned u = ((unsigned)(unsigned short)s) << 16;
    return __builtin_bit_cast(float, u);
}
__device__ __forceinline__ unsigned pack2(float a, float b) {
    return (unsigned)(unsigned short)f2bf(a) | ((unsigned)(unsigned short)f2bf(b) << 16);
}
// truncating pack (P >= 0: bias <= 1 bf16 ulp) — saves VALU in hot loop
__device__ __forceinline__ unsigned pack2t(float a, float b) {
    unsigned ua = __builtin_bit_cast(unsigned, a);
    unsigned ub = __builtin_bit_cast(unsigned, b);
    return (ua >> 16) | (ub & 0xFFFF0000u);
}

// async 16B/lane global->LDS copy (global_load_lds_dwordx4). LDS dest is
// wave-uniform base + lane*16 — forces UNPADDED tiles, so only used in the
// GEMMs (qkv/oproj) where the m97 read pattern tolerates the conflicts.
// R9 lesson: using it in attn cost ~29us of bank-conflict serialization.
__device__ __forceinline__ void async_ld16(const void* g, void* l) {
    __builtin_amdgcn_global_load_lds(
        (const __attribute__((address_space(1))) unsigned int*)g,
        (__attribute__((address_space(3))) unsigned int*)l, 16, 0, 0);
}

// ---------------------------------------------------------------------------
// Kernel 0: fp32 -> bf16 convert of x and all four weights (once per call).
// ---------------------------------------------------------------------------
__global__ __launch_bounds__(256) void convert_kernel(
    const float* __restrict__ x, const float* __restrict__ Wq,
    const float* __restrict__ Wk, const float* __restrict__ Wv,
    const float* __restrict__ Wo, short* __restrict__ xb, short* __restrict__ wb) {
    const size_t f = ((size_t)blockIdx.x * 256 + threadIdx.x) * 8;   // 8 floats/thread
    const float* src;
    short* dst;
    if (f < 4194304) { src = x + f; dst = xb + f; }
    else {
        size_t wo = f - 4194304;
        int seg = (int)(wo >> 20);
        const float* ws4[4] = {Wq, Wk, Wv, Wo};
        src = ws4[seg] + (wo & 1048575u);
        dst = wb + wo;
    }
    float4 a = ((const float4*)src)[0];
    float4 b = ((const float4*)src)[1];
    *(uint4*)dst = make_uint4(pack2(a.x, a.y), pack2(a.z, a.w),
                              pack2(b.x, b.y), pack2(b.z, b.w));
}

// ---------------------------------------------------------------------------
// Kernel 1: QKV projection, m97-structure (128x128 tile, BK=64, async stage).
// Q,K -> [B,H,T,D] bf16 (unrotated); V -> [B,H,D,T] bf16 (pre-transposed).
// RoPE stays separate: fusing it cost ~20us (VGPR cliff, R8).
// ---------------------------------------------------------------------------
__global__ __launch_bounds__(256) void qkv_kernel(
    const short* __restrict__ xb, const short* __restrict__ wb,
    short* __restrict__ Qo, short* __restrict__ Ko, short* __restrict__ VTo) {
    __shared__ __align__(16) short sA[128 * 64];
    __shared__ __align__(16) short sB[128 * 64];
    const int tid = threadIdx.x;
    const int w = tid >> 6, lane = tid & 63, quad = lane >> 4, l15 = lane & 15;
    const int wm = w & 1, wn = w >> 1;
    const int bx = blockIdx.x, by = blockIdx.y;
    const int m0 = by * 128;
    const int nb = bx * 128;

    f32x4 acc[4][4];
#pragma unroll
    for (int i = 0; i < 4; i++)
#pragma unroll
        for (int j = 0; j < 4; j++) acc[i][j] = f32x4{0.f, 0.f, 0.f, 0.f};

    for (int kb = 0; kb < 16; kb++) {
        const int k0 = kb * 64;
        if (kb) __syncthreads();
#pragma unroll
        for (int i = 0; i < 4; i++) {
            int c = i * 256 + tid;             // 16B chunk id
            int row = c >> 3, col8 = (c & 7) * 8;
            async_ld16(xb + (size_t)(m0 + row) * 1024 + k0 + col8,
                       &sA[(i * 256 + w * 64) * 8]);
            async_ld16(wb + (size_t)(nb + row) * 1024 + k0 + col8,
                       &sB[(i * 256 + w * 64) * 8]);
        }
        __syncthreads();
#pragma unroll
        for (int ks = 0; ks < 2; ks++) {
            s16x8 av[4], bv[4];
#pragma unroll
            for (int at = 0; at < 4; at++)
                av[at] = *(const s16x8*)&sA[(wm * 64 + at * 16 + l15) * 64 + ks * 32 + quad * 8];
#pragma unroll
            for (int bt = 0; bt < 4; bt++)
                bv[bt] = *(const s16x8*)&sB[(wn * 64 + bt * 16 + l15) * 64 + ks * 32 + quad * 8];
#pragma unroll
            for (int at = 0; at < 4; at++)
#pragma unroll
                for (int bt = 0; bt < 4; bt++)
                    acc[at][bt] = MFMA16(av[at], bv[bt], acc[at][bt]);
        }
    }

    const int wsel = bx >> 3;                 // 0=q 1=k 2=v
    const int h = (bx & 7) * 2 + wn;          // head (uniform per wave)
    if (wsel == 2) {
#pragma unroll
        for (int at = 0; at < 4; at++) {
            int m = m0 + wm * 64 + at * 16 + quad * 4;
            int b = m >> 11, t0 = m & 2047;
            size_t base = ((size_t)((b * 16 + h) * 64)) * 2048;
#pragma unroll
            for (int bt = 0; bt < 4; bt++) {
                int d = bt * 16 + l15;
                unsigned lo = pack2(acc[at][bt][0], acc[at][bt][1]);
                unsigned hi = pack2(acc[at][bt][2], acc[at][bt][3]);
                *(uint2*)&VTo[base + (size_t)d * 2048 + t0] = make_uint2(lo, hi);
            }
        }
    } else {
        short* Out = (wsel == 0) ? Qo : Ko;
#pragma unroll
        for (int at = 0; at < 4; at++)
#pragma unroll
            for (int r = 0; r < 4; r++) {
                int m = m0 + wm * 64 + at * 16 + quad * 4 + r;
                int b = m >> 11, t = m & 2047;
                size_t base = (((size_t)(b * 16 + h)) * 2048 + t) * 64;
#pragma unroll
                for (int bt = 0; bt < 4; bt++)
                    Out[base + bt * 16 + l15] = f2bf(acc[at][bt][r]);
            }
    }
}

// ---------------------------------------------------------------------------
// Kernel 2: RoPE in-place on Q and K. Q pre-scaled by 0.125*log2(e) (exp2
// domain softmax). Native v_sin/v_cos (revolutions).
// ---------------------------------------------------------------------------
__global__ __launch_bounds__(256) void rope_kernel(short* __restrict__ Q, short* __restrict__ K) {
    const int rid = blockIdx.x * 256 + threadIdx.x;   // 0..131071
    const bool isK = (rid & 65536) != 0;
    short* buf = isK ? K : Q;
    const float sc = isK ? 1.0f : 0.18033688011112042f;   // 1/8 * log2(e)
    const int r2 = rid & 65535;          // bh*2048 + t
    const int t = r2 & 2047;
    short* row = buf + (size_t)r2 * 64;

    unsigned wv[32];
    const uint4* rp = (const uint4*)row;
#pragma unroll
    for (int c = 0; c < 8; c++) {
        uint4 v = rp[c];
        wv[c * 4 + 0] = v.x; wv[c * 4 + 1] = v.y; wv[c * 4 + 2] = v.z; wv[c * 4 + 3] = v.w;
    }
    float y1[32], y2[32];
    const float tf = (float)t;
#pragma unroll
    for (int i = 0; i < 32; i++) {
        float x1 = bf2f((short)(wv[i] & 0xFFFFu));
        float x2 = bf2f((short)(wv[i] >> 16));
        float inv = exp2f((float)i * -0.4152410118609203f);  // 10000^(-i/32), const-folded
        float rev = tf * inv * 0.15915494309189535f;         // fr / 2pi
        rev = rev - floorf(rev);
        float sn = __builtin_amdgcn_sinf(rev);               // sin(rev*2pi) = sin(fr)
        float cs = __builtin_amdgcn_cosf(rev);
        y1[i] = (x1 * cs - x2 * sn) * sc;
        y2[i] = (x1 * sn + x2 * cs) * sc;
    }
    unsigned ow[32];
#pragma unroll
    for (int i = 0; i < 16; i++) ow[i] = pack2(y1[2 * i], y1[2 * i + 1]);
#pragma unroll
    for (int i = 0; i < 16; i++) ow[16 + i] = pack2(y2[2 * i], y2[2 * i + 1]);
    uint4* wp = (uint4*)row;
#pragma unroll
    for (int c = 0; c < 8; c++)
        wp[c] = make_uint4(ow[c * 4 + 0], ow[c * 4 + 1], ow[c * 4 + 2], ow[c * 4 + 3]);
}

// ---------------------------------------------------------------------------
// Kernel 3: causal flash attention — R8 version (best measured: 56.8us).
// 64 queries x 128-key blocks, 80 units/bh, key-split partials, NO-MAX exp2
// softmax (scores bounded; exp2(-inf)=0 masks). Manual staging into PADDED
// tiles (LDP=72 / LDW=136): conflict-free staging writes, 2-way (free) frag
// reads. Partial O + l out; combine merges.
// ---------------------------------------------------------------------------
__global__ __launch_bounds__(256) void attn_kernel(
    const short* __restrict__ Q, const short* __restrict__ K,
    const short* __restrict__ VT, short* __restrict__ paO, float* __restrict__ ml) {
    __shared__ __align__(16) short sQP[64 * LDW];   // Q (64x64) then P (64q x 128k)
    __shared__ __align__(16) short sK[128 * LDP];   // 128 keys x 64 d
    __shared__ __align__(16) short sVT[64 * LDW];   // 64 d x 128 keys

    const int tid = threadIdx.x;
    const int w = tid >> 6, lane = tid & 63, quad = lane >> 4, l15 = lane & 15;
    const int u = 79 - blockIdx.x;       // largest-qt units first
    const int bh = blockIdx.y;           // 0..31

    int qt, c;
    if (u < 8)       { qt = u; c = 0; }
    else if (u < 24) { int v = u - 8;  qt = 8 + (v >> 1); c = v & 1; }
    else if (u < 48) { int v = u - 24; qt = 16 + v / 3;   c = v - 3 * (qt - 16); }
    else             { int v = u - 48; qt = 24 + (v >> 2); c = v & 3; }
    const int kbDiag = qt >> 1;              // 128-key block containing the diagonal
    const int kb0 = c * 4;
    const int kb1 = min(kb0 + 3, kbDiag);

    const short* Qp = Q + (size_t)bh * 2048 * 64;
    const short* Kp = K + (size_t)bh * 2048 * 64;
    const short* Vp = VT + (size_t)bh * 64 * 2048;   // [d][t]

    // stage Q tile (64 rows x 64 dims) into sQP (stride LDW)
#pragma unroll
    for (int i = 0; i < 2; i++) {
        int p = tid + i * 256;       // 512 uint4 slots: 64 rows x 8
        int row = p >> 3, c8 = p & 7;
        uint4 v = *(const uint4*)(Qp + (size_t)(qt * 64 + row) * 64 + c8 * 8);
        *(uint4*)&sQP[row * LDW + c8 * 8] = v;
    }
    __syncthreads();
    s16x8 aq[2];
#pragma unroll
    for (int ks = 0; ks < 2; ks++)
        aq[ks] = *(const s16x8*)&sQP[(w * 16 + l15) * LDW + ks * 32 + quad * 8];

    f32x4 o[4];
#pragma unroll
    for (int i = 0; i < 4; i++) o[i] = f32x4{0.f, 0.f, 0.f, 0.f};
    float lrun = 0.f;                // per-lane partial sum (quad-reduced at end)
    const int q_idx = qt * 64 + w * 16 + l15;

    for (int kb = kb0; kb <= kb1; kb++) {
        __syncthreads();             // prior iter's readers done (covers aq reads iter 0)
        // stage K (128 keys x 64 d) and V^T (64 d x 128 keys): 4+4 uint4/thread
#pragma unroll
        for (int i = 0; i < 4; i++) {
            int p = tid + i * 256;
            {   // sK
                int row = p >> 3, c8 = p & 7;
                uint4 kv = *(const uint4*)(Kp + (size_t)(kb * 128 + row) * 64 + c8 * 8);
                *(uint4*)&sK[row * LDP + c8 * 8] = kv;
            }
            {   // sVT
                int row = p >> 4, c16 = p & 15;
                uint4 vv = *(const uint4*)(Vp + (size_t)row * 2048 + kb * 128 + c16 * 8);
                *(uint4*)&sVT[row * LDW + c16 * 8] = vv;
            }
        }
        __syncthreads();

        // S^T: 128 keys x 16 queries per wave. A = K rows (keys), B = Q^T.
        f32x4 sa[8];
#pragma unroll
        for (int i = 0; i < 8; i++) sa[i] = f32x4{0.f, 0.f, 0.f, 0.f};
#pragma unroll
        for (int ks = 0; ks < 2; ks++) {
#pragma unroll
            for (int ct = 0; ct < 8; ct++) {
                s16x8 kf = *(const s16x8*)&sK[(ct * 16 + l15) * LDP + ks * 32 + quad * 8];
                sa[ct] = MFMA16(kf, aq[ks], sa[ct]);
            }
        }

        float ps[8][4];
#pragma unroll
        for (int ct = 0; ct < 8; ct++)
#pragma unroll
            for (int r = 0; r < 4; r++) ps[ct][r] = sa[ct][r];

        if (kb == kbDiag) {          // uniform branch: only the diagonal block masks
#pragma unroll
            for (int ct = 0; ct < 8; ct++) {
                int kbase = kb * 128 + ct * 16 + quad * 4;
#pragma unroll
                for (int r = 0; r < 4; r++)
                    if ((kbase + r) > q_idx) ps[ct][r] = -INFINITY;
            }
        }

        // P = exp2(s) (no max subtraction), accumulate per-lane l
        float cm[8];
#pragma unroll
        for (int ct = 0; ct < 8; ct++) {
#pragma unroll
            for (int r = 0; r < 4; r++) ps[ct][r] = exp2f(ps[ct][r]);
            cm[ct] = (ps[ct][0] + ps[ct][1]) + (ps[ct][2] + ps[ct][3]);
        }
        lrun += ((cm[0] + cm[1]) + (cm[2] + cm[3])) + ((cm[4] + cm[5]) + (cm[6] + cm[7]));

        // P^T (C-layout) -> sQP rows = query (wave-private), 8x ds_write_b64
#pragma unroll
        for (int ct = 0; ct < 8; ct++) {
            unsigned lo = pack2t(ps[ct][0], ps[ct][1]);
            unsigned hi = pack2t(ps[ct][2], ps[ct][3]);
            *(uint2*)&sQP[(w * 16 + l15) * LDW + ct * 16 + quad * 4] = make_uint2(lo, hi);
        }
        // no barrier: rows are wave-private, same-wave DS ops in-order

        // O += P V  (A = P rows=query, k = 128 keys; B = V^T rows = d)
#pragma unroll
        for (int ks2 = 0; ks2 < 4; ks2++) {
            s16x8 pa = *(const s16x8*)&sQP[(w * 16 + l15) * LDW + ks2 * 32 + quad * 8];
#pragma unroll
            for (int ct = 0; ct < 4; ct++) {
                s16x8 vb = *(const s16x8*)&sVT[(ct * 16 + l15) * LDW + ks2 * 32 + quad * 8];
                o[ct] = MFMA16(pa, vb, o[ct]);
            }
        }
    }

    // epilogue: UNNORMALIZED partial O (bf16) + l (fp32, per query)
    const size_t pbase = ((size_t)(bh * 80 + u)) * 4096;
#pragma unroll
    for (int r = 0; r < 4; r++) {
        int row = w * 16 + quad * 4 + r;
#pragma unroll
        for (int ct = 0; ct < 4; ct++)
            paO[pbase + row * 64 + ct * 16 + l15] = f2bf(o[ct][r]);
    }
    lrun += __shfl_xor(lrun, 16);
    lrun += __shfl_xor(lrun, 32);
    if (quad == 0)
        ml[(bh * 80 + u) * 64 + w * 16 + l15] = lrun;
}

// ---------------------------------------------------------------------------
// Kernel 3b: combine partials (no-max scheme: L = sum l_i, Y = sum O_i / L).
// ---------------------------------------------------------------------------
__global__ __launch_bounds__(256) void combine_kernel(
    const short* __restrict__ paO, const float* __restrict__ ml, short* __restrict__ Y) {
    const int qt = blockIdx.x, bh = blockIdx.y;
    const int b = bh >> 4, h = bh & 15;
    const int nch = (qt >> 3) + 1;
    int base;
    if (qt < 8) base = qt;
    else if (qt < 16) base = 8 + 2 * (qt - 8);
    else if (qt < 24) base = 24 + 3 * (qt - 16);
    else base = 48 + 4 * (qt - 24);

    const int row = threadIdx.x >> 2;
    const int cq = (threadIdx.x & 3) * 16;

    float L = 0.f;
    for (int i = 0; i < nch; i++)
        L += ml[(bh * 80 + base + i) * 64 + row];
    const float inv = 1.0f / L;

    float acc[16];
#pragma unroll
    for (int j = 0; j < 16; j++) acc[j] = 0.f;
    for (int i = 0; i < nch; i++) {
        const short* p = paO + ((size_t)(bh * 80 + base + i)) * 4096 + row * 64 + cq;
        uint4 v0 = ((const uint4*)p)[0];
        uint4 v1 = ((const uint4*)p)[1];
        unsigned vs[8] = {v0.x, v0.y, v0.z, v0.w, v1.x, v1.y, v1.z, v1.w};
#pragma unroll
        for (int j = 0; j < 8; j++) {
            acc[2 * j + 0] += bf2f((short)(vs[j] & 0xFFFFu));
            acc[2 * j + 1] += bf2f((short)(vs[j] >> 16));
        }
    }
    const int t = qt * 64 + row;
    short* yp = Y + ((size_t)(b * 2048 + t)) * 1024 + h * 64 + cq;
    unsigned ow[8];
#pragma unroll
    for (int j = 0; j < 8; j++) ow[j] = pack2(acc[2 * j] * inv, acc[2 * j + 1] * inv);
    ((uint4*)yp)[0] = make_uint4(ow[0], ow[1], ow[2], ow[3]);
    ((uint4*)yp)[1] = make_uint4(ow[4], ow[5], ow[6], ow[7]);
}

// ---------------------------------------------------------------------------
// Kernel 4: output projection, 64x128 tiles -> grid (8,64)=512 blocks (2/CU).
// Wave w owns a 64x32 output slab. fp32 out.
// ---------------------------------------------------------------------------
__global__ __launch_bounds__(256) void oproj_kernel(
    const short* __restrict__ Yb, const short* __restrict__ Wob, float* __restrict__ out) {
    __shared__ __align__(16) short sA[64 * 64];
    __shared__ __align__(16) short sB[128 * 64];
    const int tid = threadIdx.x;
    const int w = tid >> 6, lane = tid & 63, quad = lane >> 4, l15 = lane & 15;
    const int m0 = blockIdx.y * 64;
    const int nb = blockIdx.x * 128;

    f32x4 acc[4][2];
#pragma unroll
    for (int i = 0; i < 4; i++)
#pragma unroll
        for (int j = 0; j < 2; j++) acc[i][j] = f32x4{0.f, 0.f, 0.f, 0.f};

    for (int kb = 0; kb < 16; kb++) {
        const int k0 = kb * 64;
        if (kb) __syncthreads();
#pragma unroll
        for (int i = 0; i < 2; i++) {      // A: 64x64 shorts = 512 chunks
            int c = i * 256 + tid;
            int row = c >> 3, col8 = (c & 7) * 8;
            async_ld16(Yb + (size_t)(m0 + row) * 1024 + k0 + col8,
                       &sA[(i * 256 + w * 64) * 8]);
        }
#pragma unroll
        for (int i = 0; i < 4; i++) {      // B: 128x64 shorts = 1024 chunks
            int c = i * 256 + tid;
            int row = c >> 3, col8 = (c & 7) * 8;
            async_ld16(Wob + (size_t)(nb + row) * 1024 + k0 + col8,
                       &sB[(i * 256 + w * 64) * 8]);
        }
        __syncthreads();
#pragma unroll
        for (int ks = 0; ks < 2; ks++) {
            s16x8 av[4], bv[2];
#pragma unroll
            for (int at = 0; at < 4; at++)
                av[at] = *(const s16x8*)&sA[(at * 16 + l15) * 64 + ks * 32 + quad * 8];
#pragma unroll
            for (int bt = 0; bt < 2; bt++)
                bv[bt] = *(const s16x8*)&sB[(w * 32 + bt * 16 + l15) * 64 + ks * 32 + quad * 8];
#pragma unroll
            for (int at = 0; at < 4; at++)
#pragma unroll
                for (int bt = 0; bt < 2; bt++)
                    acc[at][bt] = MFMA16(av[at], bv[bt], acc[at][bt]);
        }
    }
#pragma unroll
    for (int at = 0; at < 4; at++)
#pragma unroll
        for (int r = 0; r < 4; r++) {
            int m = m0 + at * 16 + quad * 4 + r;
#pragma unroll
            for (int bt = 0; bt < 2; bt++) {
                int n = nb + w * 32 + bt * 16 + l15;
                out[(size_t)m * 1024 + n] = acc[at][bt][r];
            }
        }
}

extern "C" void kernel_launch(void* const* d_in, const int* in_sizes, int n_in,
                              void* d_out, int out_size, void* d_ws, size_t ws_size,
                              hipStream_t stream) {
    (void)in_sizes; (void)n_in; (void)out_size; (void)ws_size;
    const float* x  = (const float*)d_in[0];
    const float* Wq = (const float*)d_in[1];
    const float* Wk = (const float*)d_in[2];
    const float* Wv = (const float*)d_in[3];
    const float* Wo = (const float*)d_in[4];
    float* out = (float*)d_out;

    const size_t NE = (size_t)2 * 16 * 2048 * 64;   // 4M elems per tensor
    short* Q   = (short*)d_ws;
    short* K   = Q + NE;
    short* VT  = K + NE;          // [B,H,D,T]
    short* Y   = VT + NE;         // attn output [B,T,C] bf16
    short* xb  = Y;               // x bf16 ALIASES Y: consumed by qkv before combine writes Y
    short* wb  = Y + NE;          // [Wq|Wk|Wv|Wo] bf16, 4M elems
    short* paO = wb + NE;         // partial O: 32 bh x 80 units x 64x64 bf16 = 21 MB
    float* ml  = (float*)(paO + (size_t)32 * 80 * 4096);   // l: 32x80x64 fp32

    convert_kernel<<<4096, 256, 0, stream>>>(x, Wq, Wk, Wv, Wo, xb, wb);
    qkv_kernel<<<dim3(24, 32), 256, 0, stream>>>(xb, wb, Q, K, VT);
    rope_kernel<<<512, 256, 0, stream>>>(Q, K);
    attn_kernel<<<dim3(80, 32), 256, 0, stream>>>(Q, K, VT, paO, ml);
    combine_kernel<<<dim3(32, 32), 256, 0, stream>>>(paO, ml, Y);
    oproj_kernel<<<dim3(8, 64), 256, 0, stream>>>(Y, wb + 3 * 1048576, out);
}